// Round 4
// baseline (325.199 us; speedup 1.0000x reference)
//
#include <hip/hip_runtime.h>

typedef __bf16 bf16x8 __attribute__((ext_vector_type(8)));
typedef __bf16 bf16x4 __attribute__((ext_vector_type(4)));
typedef __bf16 bf16x2 __attribute__((ext_vector_type(2)));
typedef float  floatx4 __attribute__((ext_vector_type(4)));

#define MFMA16(a,b,c) __builtin_amdgcn_mfma_f32_16x16x32_bf16(a,b,c,0,0,0)

constexpr int DIM  = 512;
constexpr int SEQ  = 4096;
constexpr int HD   = 64;
// 0.125 (HEAD_DIM^-0.5) * log2(e), folded into Q so softmax uses exp2 directly
constexpr float QSCALE = 0.1803368801111244f;

static __device__ inline __bf16 f2bf(float f) {
    unsigned int u = __builtin_bit_cast(unsigned int, f);
    u += 0x7fffu + ((u >> 16) & 1u);
    return __builtin_bit_cast(__bf16, (unsigned short)(u >> 16));
}
#if __has_builtin(__builtin_amdgcn_cvt_pk_bf16_f32)
static __device__ inline bf16x2 pk2(float a, float b) {
    return __builtin_amdgcn_cvt_pk_bf16_f32(a, b);
}
#else
static __device__ inline bf16x2 pk2(float a, float b) {
    bf16x2 r; r[0] = f2bf(a); r[1] = f2bf(b); return r;
}
#endif
#if __has_builtin(__builtin_amdgcn_exp2f)
#define EXP2(x) __builtin_amdgcn_exp2f(x)
#else
#define EXP2(x) exp2f(x)
#endif
static __device__ inline bf16x8 cvt8(floatx4 lo, floatx4 hi) {
    bf16x2 p0 = pk2(lo[0], lo[1]), p1 = pk2(lo[2], lo[3]);
    bf16x2 p2 = pk2(hi[0], hi[1]), p3 = pk2(hi[2], hi[3]);
    bf16x8 r;
    r[0]=p0[0]; r[1]=p0[1]; r[2]=p1[0]; r[3]=p1[1];
    r[4]=p2[0]; r[5]=p2[1]; r[6]=p3[0]; r[7]=p3[1];
    return r;
}

// ---------------------------------------------------------------------------
// Stage 1: qkv = x @ w_qkv^T + b_qkv  (fp32 in, bf16 MFMA, bf16 workspace out)
// Q pre-scaled by QSCALE. Scatter into Q/K [bh][n][64], V^T [bh][64][n].
// ---------------------------------------------------------------------------
__global__ __launch_bounds__(256)
void gemm_qkv(const float* __restrict__ X, const float* __restrict__ W,
              const float* __restrict__ bias,
              __bf16* __restrict__ Qo, __bf16* __restrict__ Ko, __bf16* __restrict__ Vt)
{
    __shared__ __bf16 As[128*32];
    __shared__ __bf16 Bs[128*32];
    const int tid  = threadIdx.x;
    const int lane = tid & 63;
    const int wave = tid >> 6;
    const int quad = lane >> 4;
    const int l16  = lane & 15;
    const int waveM = wave >> 1, waveN = wave & 1;
    const int mBase = blockIdx.y * 128;
    const int nBase = blockIdx.x * 128;

    floatx4 zero = {0.f, 0.f, 0.f, 0.f};
    floatx4 acc[4][4];
    for (int i = 0; i < 4; i++)
        for (int j = 0; j < 4; j++) acc[i][j] = zero;

    const int srow = tid >> 2;        // 0..63
    const int scol = (tid & 3) * 8;   // 0,8,16,24

    for (int k0 = 0; k0 < DIM; k0 += 32) {
        const float* xr0 = X + (size_t)(mBase + srow)      * DIM + k0 + scol;
        const float* xr1 = X + (size_t)(mBase + 64 + srow) * DIM + k0 + scol;
        const float* wr0 = W + (size_t)(nBase + srow)      * DIM + k0 + scol;
        const float* wr1 = W + (size_t)(nBase + 64 + srow) * DIM + k0 + scol;
        bf16x8 a0 = cvt8(*(const floatx4*)xr0, *(const floatx4*)(xr0 + 4));
        bf16x8 a1 = cvt8(*(const floatx4*)xr1, *(const floatx4*)(xr1 + 4));
        bf16x8 b0 = cvt8(*(const floatx4*)wr0, *(const floatx4*)(wr0 + 4));
        bf16x8 b1 = cvt8(*(const floatx4*)wr1, *(const floatx4*)(wr1 + 4));
        *(bf16x8*)&As[srow*32 + scol]      = a0;
        *(bf16x8*)&As[(64+srow)*32 + scol] = a1;
        *(bf16x8*)&Bs[srow*32 + scol]      = b0;
        *(bf16x8*)&Bs[(64+srow)*32 + scol] = b1;
        __syncthreads();
        bf16x8 af[4], bfr[4];
        for (int mi = 0; mi < 4; mi++)
            af[mi]  = *(const bf16x8*)&As[(waveM*64 + mi*16 + l16)*32 + quad*8];
        for (int ni = 0; ni < 4; ni++)
            bfr[ni] = *(const bf16x8*)&Bs[(waveN*64 + ni*16 + l16)*32 + quad*8];
        for (int mi = 0; mi < 4; mi++)
            for (int ni = 0; ni < 4; ni++)
                acc[mi][ni] = MFMA16(af[mi], bfr[ni], acc[mi][ni]);
        __syncthreads();
    }

    for (int ni = 0; ni < 4; ni++) {
        const int n = nBase + waveN*64 + ni*16 + l16;   // 0..1535
        const float bv = bias[n];
        const int which = n >> 9;          // 0=q 1=k 2=v
        const int h = (n >> 6) & 7;
        const int d = n & 63;
        for (int mi = 0; mi < 4; mi++) {
            const int m0 = mBase + waveM*64 + mi*16 + quad*4;
            for (int r = 0; r < 4; r++) {
                const int mm = m0 + r;                 // 0..8191
                const int b = mm >> 12;
                const int s = mm & 4095;
                const int bh = (b << 3) | h;
                float val = acc[mi][ni][r] + bv;
                if (which == 0) {
                    Qo[((size_t)bh*SEQ + s)*HD + d] = f2bf(val * QSCALE);
                } else if (which == 1) {
                    Ko[((size_t)bh*SEQ + s)*HD + d] = f2bf(val);
                } else {
                    Vt[((size_t)bh*HD + d)*SEQ + s] = f2bf(val);
                }
            }
        }
    }
}

// ---------------------------------------------------------------------------
// Stage 2: flash attention, transposed-tile scheme — zero LDS in main loop.
// Computes S^T = K Q^T (C layout: row=key, col=query) so exp2(S^T) packed
// in-register IS a valid PV B-operand under the key permutation
// pi(quad,j) = key0 + (j>=4)*16 + quad*4 + (j&3); V^T is loaded with the
// same permutation (two bf16x4 reads). O^T accumulated in C layout.
// Wave w handles all 64 q x keys [1024w,1024w+1024). Combine via small LDS.
// ---------------------------------------------------------------------------
__global__ __launch_bounds__(256, 3)
void attn_kernel(const __bf16* __restrict__ Q, const __bf16* __restrict__ K,
                 const __bf16* __restrict__ Vt, __bf16* __restrict__ Ao)
{
    __shared__ __bf16 Ob[3][64*68];   // bf16 partial O^T/L, stride 68
    __shared__ float  Lb[4][64];
    const int tid  = threadIdx.x;
    const int lane = tid & 63;
    const int wave = tid >> 6;
    const int quad = lane >> 4;
    const int l16  = lane & 15;
    const int bh    = blockIdx.x;         // 0..15
    const int qBase = blockIdx.y * 64;

    const __bf16* qg = Q  + ((size_t)bh*SEQ + qBase) * HD;
    const __bf16* kg = K  + (size_t)bh*SEQ*HD;
    const __bf16* vg = Vt + (size_t)bh*HD*SEQ;

    // Q as B-operand: lane l16 = query, k = d = quad*8+j
    bf16x8 qf[4][2];
    for (int t = 0; t < 4; t++) {
        const __bf16* qr = qg + (size_t)(t*16 + l16) * HD;
        qf[t][0] = *(const bf16x8*)(qr + quad*8);
        qf[t][1] = *(const bf16x8*)(qr + 32 + quad*8);
    }

    floatx4 zero = {0.f, 0.f, 0.f, 0.f};
    floatx4 oacc[4][4];   // [t][od]: O^T tile, row d=od*16+quad*4+r, col q=t*16+l16
    for (int t = 0; t < 4; t++)
        for (int od = 0; od < 4; od++) oacc[t][od] = zero;
    float Lacc[4] = {0.f, 0.f, 0.f, 0.f};

    const int key_begin = wave * 1024;
    // V^T base for this lane: row d = od*16+l16, keys at quad*4 (+16)
    const __bf16* vrow = vg + (size_t)l16 * SEQ + quad*4;

    for (int key0 = key_begin; key0 < key_begin + 1024; key0 += 32) {
        // K as A-operand: lane l16 = key (within kt tile), k = d
        bf16x8 kb[2][2];
        for (int kt = 0; kt < 2; kt++) {
            const __bf16* kr = kg + (size_t)(key0 + kt*16 + l16) * HD + quad*8;
            kb[kt][0] = *(const bf16x8*)kr;
            kb[kt][1] = *(const bf16x8*)(kr + 32);
        }
        // V^T as A-operand with permuted keys: slot j<4 -> key0+quad*4+j,
        // slot j>=4 -> key0+16+quad*4+(j-4)
        bf16x8 vb[4];
        for (int od = 0; od < 4; od++) {
            const __bf16* vr = vrow + (size_t)(od*16) * SEQ + key0;
            bf16x4 v0 = *(const bf16x4*)vr;
            bf16x4 v1 = *(const bf16x4*)(vr + 16);
            bf16x8 v;
            v[0]=v0[0]; v[1]=v0[1]; v[2]=v0[2]; v[3]=v0[3];
            v[4]=v1[0]; v[5]=v1[1]; v[6]=v1[2]; v[7]=v1[3];
            vb[od] = v;
        }

        for (int t = 0; t < 4; t++) {
            // S^T tiles: rows = keys (key0 + kt*16 + quad*4+r), cols = queries
            floatx4 z0 = zero, z1 = zero;
            z0 = MFMA16(kb[0][0], qf[t][0], z0);
            z0 = MFMA16(kb[0][1], qf[t][1], z0);
            z1 = MFMA16(kb[1][0], qf[t][0], z1);
            z1 = MFMA16(kb[1][1], qf[t][1], z1);
            float e0[4], e1[4];
            for (int r = 0; r < 4; r++) { e0[r] = EXP2(z0[r]); e1[r] = EXP2(z1[r]); }
            Lacc[t] += (e0[0]+e0[1]+e0[2]+e0[3]) + (e1[0]+e1[1]+e1[2]+e1[3]);
            // P^T B-operand: slots 0..3 = kt0 rows, 4..7 = kt1 rows (pi-permuted)
            bf16x2 p0 = pk2(e0[0], e0[1]), p1 = pk2(e0[2], e0[3]);
            bf16x2 p2 = pk2(e1[0], e1[1]), p3 = pk2(e1[2], e1[3]);
            bf16x8 pb;
            pb[0]=p0[0]; pb[1]=p0[1]; pb[2]=p1[0]; pb[3]=p1[1];
            pb[4]=p2[0]; pb[5]=p2[1]; pb[6]=p3[0]; pb[7]=p3[1];
            for (int od = 0; od < 4; od++)
                oacc[t][od] = MFMA16(vb[od], pb, oacc[t][od]);
        }
    }

    // L: sum across quads (rows of S^T live on different quads, same l16=q)
    for (int t = 0; t < 4; t++) {
        float l = Lacc[t];
        l += __shfl_xor(l, 16);
        l += __shfl_xor(l, 32);
        Lacc[t] = l;
    }
    if (lane < 16)
        for (int t = 0; t < 4; t++) Lb[wave][t*16 + lane] = Lacc[t];
    __syncthreads();
    float inv[4];
    for (int t = 0; t < 4; t++) {
        const int q = t*16 + l16;
        inv[t] = 1.0f / (Lb[0][q] + Lb[1][q] + Lb[2][q] + Lb[3][q]);
    }
    if (wave != 0) {
        for (int t = 0; t < 4; t++)
            for (int od = 0; od < 4; od++) {
                bf16x4 v;
                for (int r = 0; r < 4; r++) v[r] = f2bf(oacc[t][od][r] * inv[t]);
                *(bf16x4*)&Ob[wave-1][(t*16 + l16)*68 + od*16 + quad*4] = v;
            }
    }
    __syncthreads();
    if (wave == 0) {
        const int b = bh >> 3, h = bh & 7;
        for (int t = 0; t < 4; t++) {
            const int s = qBase + t*16 + l16;
            for (int od = 0; od < 4; od++) {
                bf16x4 o0 = *(const bf16x4*)&Ob[0][(t*16 + l16)*68 + od*16 + quad*4];
                bf16x4 o1 = *(const bf16x4*)&Ob[1][(t*16 + l16)*68 + od*16 + quad*4];
                bf16x4 o2 = *(const bf16x4*)&Ob[2][(t*16 + l16)*68 + od*16 + quad*4];
                bf16x4 v;
                for (int r = 0; r < 4; r++) {
                    float o = oacc[t][od][r] * inv[t] +
                              (float)o0[r] + (float)o1[r] + (float)o2[r];
                    v[r] = f2bf(o);
                }
                *(bf16x4*)&Ao[((size_t)(b*SEQ + s))*DIM + h*HD + od*16 + quad*4] = v;
            }
        }
    }
}

// ---------------------------------------------------------------------------
// Stage 3: out = attn_out @ w_proj^T + b_proj  (bf16 A, fp32 W in, fp32 out)
// ---------------------------------------------------------------------------
__global__ __launch_bounds__(256)
void gemm_proj(const __bf16* __restrict__ A, const float* __restrict__ W,
               const float* __restrict__ bias, float* __restrict__ Out)
{
    __shared__ __bf16 As[128*32];
    __shared__ __bf16 Bs[128*32];
    const int tid  = threadIdx.x;
    const int lane = tid & 63;
    const int wave = tid >> 6;
    const int quad = lane >> 4;
    const int l16  = lane & 15;
    const int waveM = wave >> 1, waveN = wave & 1;
    const int mBase = blockIdx.y * 128;
    const int nBase = blockIdx.x * 128;

    floatx4 zero = {0.f, 0.f, 0.f, 0.f};
    floatx4 acc[4][4];
    for (int i = 0; i < 4; i++)
        for (int j = 0; j < 4; j++) acc[i][j] = zero;

    const int srow = tid >> 2;
    const int scol = (tid & 3) * 8;

    for (int k0 = 0; k0 < DIM; k0 += 32) {
        bf16x8 a0 = *(const bf16x8*)(A + (size_t)(mBase + srow)      * DIM + k0 + scol);
        bf16x8 a1 = *(const bf16x8*)(A + (size_t)(mBase + 64 + srow) * DIM + k0 + scol);
        const float* wr0 = W + (size_t)(nBase + srow)      * DIM + k0 + scol;
        const float* wr1 = W + (size_t)(nBase + 64 + srow) * DIM + k0 + scol;
        bf16x8 b0 = cvt8(*(const floatx4*)wr0, *(const floatx4*)(wr0 + 4));
        bf16x8 b1 = cvt8(*(const floatx4*)wr1, *(const floatx4*)(wr1 + 4));
        *(bf16x8*)&As[srow*32 + scol]      = a0;
        *(bf16x8*)&As[(64+srow)*32 + scol] = a1;
        *(bf16x8*)&Bs[srow*32 + scol]      = b0;
        *(bf16x8*)&Bs[(64+srow)*32 + scol] = b1;
        __syncthreads();
        bf16x8 af[4], bfr[4];
        for (int mi = 0; mi < 4; mi++)
            af[mi]  = *(const bf16x8*)&As[(waveM*64 + mi*16 + l16)*32 + quad*8];
        for (int ni = 0; ni < 4; ni++)
            bfr[ni] = *(const bf16x8*)&Bs[(waveN*64 + ni*16 + l16)*32 + quad*8];
        for (int mi = 0; mi < 4; mi++)
            for (int ni = 0; ni < 4; ni++)
                acc[mi][ni] = MFMA16(af[mi], bfr[ni], acc[mi][ni]);
        __syncthreads();
    }

    for (int ni = 0; ni < 4; ni++) {
        const int n = nBase + waveN*64 + ni*16 + l16;
        const float bv = bias[n];
        for (int mi = 0; mi < 4; mi++) {
            const int m0 = mBase + waveM*64 + mi*16 + quad*4;
            for (int r = 0; r < 4; r++) {
                const int mm = m0 + r;
                Out[(size_t)mm*DIM + n] = acc[mi][ni][r] + bv;
            }
        }
    }
}

extern "C" void kernel_launch(void* const* d_in, const int* in_sizes, int n_in,
                              void* d_out, int out_size, void* d_ws, size_t ws_size,
                              hipStream_t stream) {
    const float* x      = (const float*)d_in[0];   // [2,4096,512] fp32
    const float* w_qkv  = (const float*)d_in[1];   // [1536,512] fp32
    const float* b_qkv  = (const float*)d_in[2];   // [1536] fp32
    const float* w_proj = (const float*)d_in[3];   // [512,512] fp32
    const float* b_proj = (const float*)d_in[4];   // [512] fp32
    float* out = (float*)d_out;                    // [2,4096,512] fp32

    __bf16* ws  = (__bf16*)d_ws;
    const size_t PLANE = (size_t)16 * SEQ * HD;    // 4 Mi elements = 8 MB
    __bf16* Qb  = ws;                 // [16][4096][64] (pre-scaled by QSCALE*log2e)
    __bf16* Kb  = ws + PLANE;         // [16][4096][64]
    __bf16* Vtb = ws + 2*PLANE;       // [16][64][4096]
    __bf16* Aob = ws + 3*PLANE;       // [2,4096,512] attention output (bf16)

    gemm_qkv<<<dim3(12, 64), 256, 0, stream>>>(x, w_qkv, b_qkv, Qb, Kb, Vtb);
    attn_kernel<<<dim3(16, 64), 256, 0, stream>>>(Qb, Kb, Vtb, Aob);
    gemm_proj<<<dim3(4, 64), 256, 0, stream>>>(Aob, w_proj, b_proj, out);
}

// Round 5
// 236.083 us; speedup vs baseline: 1.3775x; 1.3775x over previous
//
#include <hip/hip_runtime.h>

typedef __bf16 bf16x8 __attribute__((ext_vector_type(8)));
typedef __bf16 bf16x4 __attribute__((ext_vector_type(4)));
typedef __bf16 bf16x2 __attribute__((ext_vector_type(2)));
typedef float  floatx4 __attribute__((ext_vector_type(4)));

#define MFMA16(a,b,c) __builtin_amdgcn_mfma_f32_16x16x32_bf16(a,b,c,0,0,0)

constexpr int DIM  = 512;
constexpr int SEQ  = 4096;
constexpr int HD   = 64;
// 0.125 (HEAD_DIM^-0.5) * log2(e), folded into Q so softmax uses exp2 directly
constexpr float QSCALE = 0.1803368801111244f;

static __device__ inline __bf16 f2bf(float f) {
    unsigned int u = __builtin_bit_cast(unsigned int, f);
    u += 0x7fffu + ((u >> 16) & 1u);
    return __builtin_bit_cast(__bf16, (unsigned short)(u >> 16));
}
#if __has_builtin(__builtin_amdgcn_cvt_pk_bf16_f32)
static __device__ inline bf16x2 pk2(float a, float b) {
    return __builtin_amdgcn_cvt_pk_bf16_f32(a, b);
}
#else
static __device__ inline bf16x2 pk2(float a, float b) {
    bf16x2 r; r[0] = f2bf(a); r[1] = f2bf(b); return r;
}
#endif
#if __has_builtin(__builtin_amdgcn_exp2f)
#define EXP2(x) __builtin_amdgcn_exp2f(x)
#else
#define EXP2(x) exp2f(x)
#endif
static __device__ inline bf16x8 cvt8(floatx4 lo, floatx4 hi) {
    bf16x2 p0 = pk2(lo[0], lo[1]), p1 = pk2(lo[2], lo[3]);
    bf16x2 p2 = pk2(hi[0], hi[1]), p3 = pk2(hi[2], hi[3]);
    bf16x8 r;
    r[0]=p0[0]; r[1]=p0[1]; r[2]=p1[0]; r[3]=p1[1];
    r[4]=p2[0]; r[5]=p2[1]; r[6]=p3[0]; r[7]=p3[1];
    return r;
}

// ---------------------------------------------------------------------------
// Stage 1: qkv = x @ w_qkv^T + b_qkv  (fp32 in, bf16 MFMA, bf16 workspace out)
// Q pre-scaled by QSCALE -> [bh][s][64].
// K pre-blocked into MFMA A-fragment order: Kblk[bh][s>>4][d>>5][lane][8]
//   where lane = ((d>>3)&3)*16 + (s&15), slot j = d&7.
// V pre-blocked under key-permutation pi(q,j)=16*(j>=4)+4q+(j&3):
//   Vblk[bh][s>>5][d>>4][lane][8], lane = ((s>>2)&3)*16 + (d&15),
//   slot j = (s&3) + ((s>>4)&1)*4.
// Both are read as single fully-coalesced b128 loads in the attention loop.
// ---------------------------------------------------------------------------
__global__ __launch_bounds__(256)
void gemm_qkv(const float* __restrict__ X, const float* __restrict__ W,
              const float* __restrict__ bias,
              __bf16* __restrict__ Qo, __bf16* __restrict__ Kb, __bf16* __restrict__ Vb)
{
    __shared__ __bf16 As[128*32];
    __shared__ __bf16 Bs[128*32];
    const int tid  = threadIdx.x;
    const int lane = tid & 63;
    const int wave = tid >> 6;
    const int quad = lane >> 4;
    const int l16  = lane & 15;
    const int waveM = wave >> 1, waveN = wave & 1;
    const int mBase = blockIdx.y * 128;
    const int nBase = blockIdx.x * 128;

    floatx4 zero = {0.f, 0.f, 0.f, 0.f};
    floatx4 acc[4][4];
    for (int i = 0; i < 4; i++)
        for (int j = 0; j < 4; j++) acc[i][j] = zero;

    const int srow = tid >> 2;        // 0..63
    const int scol = (tid & 3) * 8;   // 0,8,16,24

    for (int k0 = 0; k0 < DIM; k0 += 32) {
        const float* xr0 = X + (size_t)(mBase + srow)      * DIM + k0 + scol;
        const float* xr1 = X + (size_t)(mBase + 64 + srow) * DIM + k0 + scol;
        const float* wr0 = W + (size_t)(nBase + srow)      * DIM + k0 + scol;
        const float* wr1 = W + (size_t)(nBase + 64 + srow) * DIM + k0 + scol;
        bf16x8 a0 = cvt8(*(const floatx4*)xr0, *(const floatx4*)(xr0 + 4));
        bf16x8 a1 = cvt8(*(const floatx4*)xr1, *(const floatx4*)(xr1 + 4));
        bf16x8 b0 = cvt8(*(const floatx4*)wr0, *(const floatx4*)(wr0 + 4));
        bf16x8 b1 = cvt8(*(const floatx4*)wr1, *(const floatx4*)(wr1 + 4));
        *(bf16x8*)&As[srow*32 + scol]      = a0;
        *(bf16x8*)&As[(64+srow)*32 + scol] = a1;
        *(bf16x8*)&Bs[srow*32 + scol]      = b0;
        *(bf16x8*)&Bs[(64+srow)*32 + scol] = b1;
        __syncthreads();
        bf16x8 af[4], bfr[4];
        for (int mi = 0; mi < 4; mi++)
            af[mi]  = *(const bf16x8*)&As[(waveM*64 + mi*16 + l16)*32 + quad*8];
        for (int ni = 0; ni < 4; ni++)
            bfr[ni] = *(const bf16x8*)&Bs[(waveN*64 + ni*16 + l16)*32 + quad*8];
        for (int mi = 0; mi < 4; mi++)
            for (int ni = 0; ni < 4; ni++)
                acc[mi][ni] = MFMA16(af[mi], bfr[ni], acc[mi][ni]);
        __syncthreads();
    }

    for (int ni = 0; ni < 4; ni++) {
        const int n = nBase + waveN*64 + ni*16 + l16;   // 0..1535
        const float bv = bias[n];
        const int which = n >> 9;          // 0=q 1=k 2=v
        const int h = (n >> 6) & 7;
        const int d = n & 63;
        for (int mi = 0; mi < 4; mi++) {
            const int m0 = mBase + waveM*64 + mi*16 + quad*4;   // mult of 4
            const int b  = m0 >> 12;
            const int s0 = m0 & 4095;
            const int bh = (b << 3) | h;
            if (which == 0) {
                for (int r = 0; r < 4; r++)
                    Qo[((size_t)bh*SEQ + s0 + r)*HD + d] =
                        f2bf((acc[mi][ni][r] + bv) * QSCALE);
            } else if (which == 1) {
                // Kblk: lane = ((d>>3)&3)*16 + (s&15), slot = d&7
                for (int r = 0; r < 4; r++) {
                    const int s = s0 + r;
                    size_t off = (((((size_t)bh*256 + (s >> 4))*2 + (d >> 5))*64)
                                  + ((d >> 3) & 3)*16 + (s & 15))*8 + (d & 7);
                    Kb[off] = f2bf(acc[mi][ni][r] + bv);
                }
            } else {
                // Vblk: r=0..3 -> consecutive slots j0..j0+3 (one 8B store)
                bf16x4 v;
                for (int r = 0; r < 4; r++) v[r] = f2bf(acc[mi][ni][r] + bv);
                size_t off = (((((size_t)bh*128 + (s0 >> 5))*4 + (d >> 4))*64)
                              + ((s0 >> 2) & 3)*16 + (d & 15))*8 + ((s0 >> 4) & 1)*4;
                *(bf16x4*)&Vb[off] = v;
            }
        }
    }
}

// ---------------------------------------------------------------------------
// Stage 2: flash attention, transposed-tile scheme — zero LDS in main loop,
// all K/V fragment loads fully-coalesced b128 from pre-blocked workspace.
// S^T = K Q^T (C layout row=key col=query); exp2(S^T) packed in-register is
// the PV B-operand under pi; O^T accumulated in C layout.
// Wave w handles all 64 q x keys [1024w,1024w+1024). Combine via small LDS.
// ---------------------------------------------------------------------------
__global__ __launch_bounds__(256, 3)
void attn_kernel(const __bf16* __restrict__ Q, const __bf16* __restrict__ Kb,
                 const __bf16* __restrict__ Vb, __bf16* __restrict__ Ao)
{
    __shared__ __bf16 Ob[3][64*68];   // bf16 partial O^T, stride 68
    __shared__ float  Lb[4][64];
    const int tid  = threadIdx.x;
    const int lane = tid & 63;
    const int wave = tid >> 6;
    const int quad = lane >> 4;
    const int l16  = lane & 15;
    const int bh    = blockIdx.x;         // 0..15
    const int qBase = blockIdx.y * 64;

    const __bf16* qg = Q  + ((size_t)bh*SEQ + qBase) * HD;
    const __bf16* kg = Kb + (size_t)bh*256*2*64*8;   // [kt16][hb][lane][8]
    const __bf16* vg = Vb + (size_t)bh*128*4*64*8;   // [kb32][od][lane][8]

    // Q as B-operand: lane l16 = query, k = d = quad*8+j (per half hb)
    bf16x8 qf[4][2];
    for (int t = 0; t < 4; t++) {
        const __bf16* qr = qg + (size_t)(t*16 + l16) * HD;
        qf[t][0] = *(const bf16x8*)(qr + quad*8);
        qf[t][1] = *(const bf16x8*)(qr + 32 + quad*8);
    }

    floatx4 zero = {0.f, 0.f, 0.f, 0.f};
    floatx4 oacc[4][4];   // [t][od]: O^T tile, row d=od*16+quad*4+r, col q=t*16+l16
    for (int t = 0; t < 4; t++)
        for (int od = 0; od < 4; od++) oacc[t][od] = zero;
    float Lacc[4] = {0.f, 0.f, 0.f, 0.f};

    const int key_begin = wave * 1024;

    for (int key0 = key_begin; key0 < key_begin + 1024; key0 += 32) {
        // K fragments: one coalesced b128 per (kt,hb)
        const __bf16* kbase = kg + ((size_t)(key0 >> 4) * 2) * 512 + lane*8;
        bf16x8 kb[2][2];
        for (int kt = 0; kt < 2; kt++)
            for (int hb = 0; hb < 2; hb++)
                kb[kt][hb] = *(const bf16x8*)(kbase + ((size_t)kt*2 + hb)*512);
        // V fragments: one coalesced b128 per od (pi-permuted packing)
        const __bf16* vbase = vg + ((size_t)(key0 >> 5) * 4) * 512 + lane*8;
        bf16x8 vb[4];
        for (int od = 0; od < 4; od++)
            vb[od] = *(const bf16x8*)(vbase + (size_t)od*512);

        for (int t = 0; t < 4; t++) {
            // S^T tiles: rows = keys (key0 + kt*16 + quad*4+r), cols = queries
            floatx4 z0 = zero, z1 = zero;
            z0 = MFMA16(kb[0][0], qf[t][0], z0);
            z0 = MFMA16(kb[0][1], qf[t][1], z0);
            z1 = MFMA16(kb[1][0], qf[t][0], z1);
            z1 = MFMA16(kb[1][1], qf[t][1], z1);
            float e0[4], e1[4];
            for (int r = 0; r < 4; r++) { e0[r] = EXP2(z0[r]); e1[r] = EXP2(z1[r]); }
            Lacc[t] += (e0[0]+e0[1]+e0[2]+e0[3]) + (e1[0]+e1[1]+e1[2]+e1[3]);
            // P^T B-operand: slots 0..3 = kt0 rows, 4..7 = kt1 rows (pi)
            bf16x2 p0 = pk2(e0[0], e0[1]), p1 = pk2(e0[2], e0[3]);
            bf16x2 p2 = pk2(e1[0], e1[1]), p3 = pk2(e1[2], e1[3]);
            bf16x8 pb;
            pb[0]=p0[0]; pb[1]=p0[1]; pb[2]=p1[0]; pb[3]=p1[1];
            pb[4]=p2[0]; pb[5]=p2[1]; pb[6]=p3[0]; pb[7]=p3[1];
            for (int od = 0; od < 4; od++)
                oacc[t][od] = MFMA16(vb[od], pb, oacc[t][od]);
        }
    }

    // L: sum across quads (rows of S^T live on different quads, same l16=q)
    for (int t = 0; t < 4; t++) {
        float l = Lacc[t];
        l += __shfl_xor(l, 16);
        l += __shfl_xor(l, 32);
        Lacc[t] = l;
    }
    if (lane < 16)
        for (int t = 0; t < 4; t++) Lb[wave][t*16 + lane] = Lacc[t];
    __syncthreads();
    float inv[4];
    for (int t = 0; t < 4; t++) {
        const int q = t*16 + l16;
        inv[t] = 1.0f / (Lb[0][q] + Lb[1][q] + Lb[2][q] + Lb[3][q]);
    }
    if (wave != 0) {
        for (int t = 0; t < 4; t++)
            for (int od = 0; od < 4; od++) {
                bf16x4 v;
                for (int r = 0; r < 4; r++) v[r] = f2bf(oacc[t][od][r] * inv[t]);
                *(bf16x4*)&Ob[wave-1][(t*16 + l16)*68 + od*16 + quad*4] = v;
            }
    }
    __syncthreads();
    if (wave == 0) {
        const int b = bh >> 3, h = bh & 7;
        for (int t = 0; t < 4; t++) {
            const int s = qBase + t*16 + l16;
            for (int od = 0; od < 4; od++) {
                bf16x4 o0 = *(const bf16x4*)&Ob[0][(t*16 + l16)*68 + od*16 + quad*4];
                bf16x4 o1 = *(const bf16x4*)&Ob[1][(t*16 + l16)*68 + od*16 + quad*4];
                bf16x4 o2 = *(const bf16x4*)&Ob[2][(t*16 + l16)*68 + od*16 + quad*4];
                bf16x4 v;
                for (int r = 0; r < 4; r++) {
                    float o = oacc[t][od][r] * inv[t] +
                              (float)o0[r] + (float)o1[r] + (float)o2[r];
                    v[r] = f2bf(o);
                }
                *(bf16x4*)&Ao[((size_t)(b*SEQ + s))*DIM + h*HD + od*16 + quad*4] = v;
            }
        }
    }
}

// ---------------------------------------------------------------------------
// Stage 3: out = attn_out @ w_proj^T + b_proj  (bf16 A, fp32 W in, fp32 out)
// ---------------------------------------------------------------------------
__global__ __launch_bounds__(256)
void gemm_proj(const __bf16* __restrict__ A, const float* __restrict__ W,
               const float* __restrict__ bias, float* __restrict__ Out)
{
    __shared__ __bf16 As[128*32];
    __shared__ __bf16 Bs[128*32];
    const int tid  = threadIdx.x;
    const int lane = tid & 63;
    const int wave = tid >> 6;
    const int quad = lane >> 4;
    const int l16  = lane & 15;
    const int waveM = wave >> 1, waveN = wave & 1;
    const int mBase = blockIdx.y * 128;
    const int nBase = blockIdx.x * 128;

    floatx4 zero = {0.f, 0.f, 0.f, 0.f};
    floatx4 acc[4][4];
    for (int i = 0; i < 4; i++)
        for (int j = 0; j < 4; j++) acc[i][j] = zero;

    const int srow = tid >> 2;
    const int scol = (tid & 3) * 8;

    for (int k0 = 0; k0 < DIM; k0 += 32) {
        bf16x8 a0 = *(const bf16x8*)(A + (size_t)(mBase + srow)      * DIM + k0 + scol);
        bf16x8 a1 = *(const bf16x8*)(A + (size_t)(mBase + 64 + srow) * DIM + k0 + scol);
        const float* wr0 = W + (size_t)(nBase + srow)      * DIM + k0 + scol;
        const float* wr1 = W + (size_t)(nBase + 64 + srow) * DIM + k0 + scol;
        bf16x8 b0 = cvt8(*(const floatx4*)wr0, *(const floatx4*)(wr0 + 4));
        bf16x8 b1 = cvt8(*(const floatx4*)wr1, *(const floatx4*)(wr1 + 4));
        *(bf16x8*)&As[srow*32 + scol]      = a0;
        *(bf16x8*)&As[(64+srow)*32 + scol] = a1;
        *(bf16x8*)&Bs[srow*32 + scol]      = b0;
        *(bf16x8*)&Bs[(64+srow)*32 + scol] = b1;
        __syncthreads();
        bf16x8 af[4], bfr[4];
        for (int mi = 0; mi < 4; mi++)
            af[mi]  = *(const bf16x8*)&As[(waveM*64 + mi*16 + l16)*32 + quad*8];
        for (int ni = 0; ni < 4; ni++)
            bfr[ni] = *(const bf16x8*)&Bs[(waveN*64 + ni*16 + l16)*32 + quad*8];
        for (int mi = 0; mi < 4; mi++)
            for (int ni = 0; ni < 4; ni++)
                acc[mi][ni] = MFMA16(af[mi], bfr[ni], acc[mi][ni]);
        __syncthreads();
    }

    for (int ni = 0; ni < 4; ni++) {
        const int n = nBase + waveN*64 + ni*16 + l16;
        const float bv = bias[n];
        for (int mi = 0; mi < 4; mi++) {
            const int m0 = mBase + waveM*64 + mi*16 + quad*4;
            for (int r = 0; r < 4; r++) {
                const int mm = m0 + r;
                Out[(size_t)mm*DIM + n] = acc[mi][ni][r] + bv;
            }
        }
    }
}

extern "C" void kernel_launch(void* const* d_in, const int* in_sizes, int n_in,
                              void* d_out, int out_size, void* d_ws, size_t ws_size,
                              hipStream_t stream) {
    const float* x      = (const float*)d_in[0];   // [2,4096,512] fp32
    const float* w_qkv  = (const float*)d_in[1];   // [1536,512] fp32
    const float* b_qkv  = (const float*)d_in[2];   // [1536] fp32
    const float* w_proj = (const float*)d_in[3];   // [512,512] fp32
    const float* b_proj = (const float*)d_in[4];   // [512] fp32
    float* out = (float*)d_out;                    // [2,4096,512] fp32

    __bf16* ws  = (__bf16*)d_ws;
    const size_t PLANE = (size_t)16 * SEQ * HD;    // 4 Mi elements = 8 MB
    __bf16* Qb  = ws;                 // [16][4096][64] (pre-scaled)
    __bf16* Kbk = ws + PLANE;         // Kblk [16][256][2][64][8]
    __bf16* Vbk = ws + 2*PLANE;       // Vblk [16][128][4][64][8]
    __bf16* Aob = ws + 3*PLANE;       // [2,4096,512] attention output (bf16)

    gemm_qkv<<<dim3(12, 64), 256, 0, stream>>>(x, w_qkv, b_qkv, Qb, Kbk, Vbk);
    attn_kernel<<<dim3(16, 64), 256, 0, stream>>>(Qb, Kbk, Vbk, Aob);
    gemm_proj<<<dim3(4, 64), 256, 0, stream>>>(Aob, w_proj, b_proj, out);
}